// Round 1
// baseline (1318.884 us; speedup 1.0000x reference)
//
#include <hip/hip_runtime.h>

// SpatialBottleneck: x[32,1024,28,28] ->
//   conv1 1x1 (1024->256) + BN + ReLU    -> y1p [32,256,30,30] (zero-padded)
//   conv2 3x3 pad1 (256->256) + BN + ReLU -> y2 [32,256,28,28]
//   conv3 1x1 (256->1024) + BN + x + ReLU -> out [32,1024,28,28]
// Round 0: fp32 tiled-GEMM correctness baseline. 64x64 block tile, 16 k-slice,
// 4x4 per-thread microtile. MFMA/bf16 conversion planned next round.

#define TILE 64
#define KT 16

__global__ __launch_bounds__(256) void zero_f4(float4* __restrict__ p, int n4) {
    int i = blockIdx.x * blockDim.x + threadIdx.x;
    if (i < n4) p[i] = make_float4(0.f, 0.f, 0.f, 0.f);
}

// ---------------- conv1: 1x1, Cin=1024 -> Cb=256, BN+ReLU, write padded ----------------
__global__ __launch_bounds__(256) void conv1_bn_relu(
    const float* __restrict__ x, const float* __restrict__ w1,
    const float* __restrict__ g, const float* __restrict__ b,
    const float* __restrict__ m, const float* __restrict__ v,
    float* __restrict__ y1p) {
    const int HW = 784, Cin = 1024, Cb = 256;
    __shared__ float Wt[KT][TILE];
    __shared__ float Xt[KT][TILE];
    const int tid = threadIdx.x;
    const int tx = tid & 15, ty = tid >> 4;
    const int pb = blockIdx.x * TILE;      // pixel base
    const int cb = blockIdx.y * TILE;      // out-channel base
    const int n  = blockIdx.z;
    const int wr = tid >> 2;               // 0..63  (W row)
    const int wk = (tid & 3) * 4;          // 0,4,8,12
    const int xk = tid >> 4;               // 0..15
    const int xj = (tid & 15) * 4;         // 0..60
    const float* xb = x + (size_t)n * Cin * HW;
    float acc[4][4] = {};
    for (int k0 = 0; k0 < Cin; k0 += KT) {
        __syncthreads();
        float4 wv = *(const float4*)(w1 + (size_t)(cb + wr) * Cin + k0 + wk);
        Wt[wk + 0][wr] = wv.x; Wt[wk + 1][wr] = wv.y;
        Wt[wk + 2][wr] = wv.z; Wt[wk + 3][wr] = wv.w;
        float4 xv = make_float4(0.f, 0.f, 0.f, 0.f);
        if (pb + xj < HW) xv = *(const float4*)(xb + (size_t)(k0 + xk) * HW + pb + xj);
        *(float4*)&Xt[xk][xj] = xv;
        __syncthreads();
        #pragma unroll
        for (int kk = 0; kk < KT; ++kk) {
            float4 a4 = *(const float4*)&Wt[kk][ty * 4];
            float4 b4 = *(const float4*)&Xt[kk][tx * 4];
            float a[4] = {a4.x, a4.y, a4.z, a4.w};
            float bb[4] = {b4.x, b4.y, b4.z, b4.w};
            #pragma unroll
            for (int i2 = 0; i2 < 4; ++i2)
                #pragma unroll
                for (int j2 = 0; j2 < 4; ++j2)
                    acc[i2][j2] = fmaf(a[i2], bb[j2], acc[i2][j2]);
        }
    }
    #pragma unroll
    for (int i2 = 0; i2 < 4; ++i2) {
        int co = cb + ty * 4 + i2;
        float sc = g[co] * rsqrtf(v[co]);
        float bi = b[co] - m[co] * sc;
        float* dst = y1p + (size_t)(n * Cb + co) * 900;
        #pragma unroll
        for (int j2 = 0; j2 < 4; ++j2) {
            int p = pb + tx * 4 + j2;
            if (p < HW) {
                int h = p / 28, w = p - h * 28;
                float val = fmaf(acc[i2][j2], sc, bi);
                dst[(h + 1) * 30 + (w + 1)] = val > 0.f ? val : 0.f;
            }
        }
    }
}

// ---------------- conv2: 3x3 pad1, Cb->Cb, BN+ReLU ----------------
__global__ __launch_bounds__(256) void conv2_bn_relu(
    const float* __restrict__ y1p, const float* __restrict__ w2,
    const float* __restrict__ g, const float* __restrict__ b,
    const float* __restrict__ m, const float* __restrict__ v,
    float* __restrict__ y2) {
    const int HW = 784, Cb = 256;
    __shared__ float Wt[KT][TILE];
    __shared__ float Xt[KT][TILE];
    const int tid = threadIdx.x;
    const int tx = tid & 15, ty = tid >> 4;
    const int pb = blockIdx.x * TILE;
    const int cb = blockIdx.y * TILE;
    const int n  = blockIdx.z;
    const int wr = tid >> 2;
    const int wk = (tid & 3) * 4;
    const int xk = tid >> 4;
    const int xj = (tid & 15) * 4;
    // precompute padded-layout offsets for this thread's 4 staging pixels
    int q[4];
    #pragma unroll
    for (int u = 0; u < 4; ++u) {
        int p = pb + xj + u;
        if (p < HW) { int h = p / 28, w = p - h * 28; q[u] = h * 30 + w; }
        else q[u] = -1;
    }
    float acc[4][4] = {};
    for (int kh = 0; kh < 3; ++kh)
    for (int kw = 0; kw < 3; ++kw) {
        for (int k0 = 0; k0 < Cb; k0 += KT) {
            __syncthreads();
            #pragma unroll
            for (int u = 0; u < 4; ++u)
                Wt[wk + u][wr] =
                    w2[((size_t)((cb + wr) * Cb + k0 + wk + u) * 3 + kh) * 3 + kw];
            const float* src = y1p + (size_t)(n * Cb + k0 + xk) * 900 + kh * 30 + kw;
            float vals[4];
            #pragma unroll
            for (int u = 0; u < 4; ++u)
                vals[u] = (q[u] >= 0) ? src[q[u]] : 0.f;
            *(float4*)&Xt[xk][xj] = make_float4(vals[0], vals[1], vals[2], vals[3]);
            __syncthreads();
            #pragma unroll
            for (int kk = 0; kk < KT; ++kk) {
                float4 a4 = *(const float4*)&Wt[kk][ty * 4];
                float4 b4 = *(const float4*)&Xt[kk][tx * 4];
                float a[4] = {a4.x, a4.y, a4.z, a4.w};
                float bb[4] = {b4.x, b4.y, b4.z, b4.w};
                #pragma unroll
                for (int i2 = 0; i2 < 4; ++i2)
                    #pragma unroll
                    for (int j2 = 0; j2 < 4; ++j2)
                        acc[i2][j2] = fmaf(a[i2], bb[j2], acc[i2][j2]);
            }
        }
    }
    #pragma unroll
    for (int i2 = 0; i2 < 4; ++i2) {
        int co = cb + ty * 4 + i2;
        float sc = g[co] * rsqrtf(v[co]);
        float bi = b[co] - m[co] * sc;
        int p4 = pb + tx * 4;
        if (p4 < HW) {
            float4 o;
            float t0 = fmaf(acc[i2][0], sc, bi); o.x = t0 > 0.f ? t0 : 0.f;
            float t1 = fmaf(acc[i2][1], sc, bi); o.y = t1 > 0.f ? t1 : 0.f;
            float t2 = fmaf(acc[i2][2], sc, bi); o.z = t2 > 0.f ? t2 : 0.f;
            float t3 = fmaf(acc[i2][3], sc, bi); o.w = t3 > 0.f ? t3 : 0.f;
            *(float4*)(y2 + (size_t)(n * Cb + co) * HW + p4) = o;
        }
    }
}

// ---------------- conv3: 1x1, Cb=256 -> Cout=1024, BN + residual + ReLU ----------------
__global__ __launch_bounds__(256) void conv3_bn_add_relu(
    const float* __restrict__ y2, const float* __restrict__ w3,
    const float* __restrict__ g, const float* __restrict__ b,
    const float* __restrict__ m, const float* __restrict__ v,
    const float* __restrict__ x, float* __restrict__ out) {
    const int HW = 784, Cb = 256, Cout = 1024;
    __shared__ float Wt[KT][TILE];
    __shared__ float Xt[KT][TILE];
    const int tid = threadIdx.x;
    const int tx = tid & 15, ty = tid >> 4;
    const int pb = blockIdx.x * TILE;
    const int cb = blockIdx.y * TILE;
    const int n  = blockIdx.z;
    const int wr = tid >> 2;
    const int wk = (tid & 3) * 4;
    const int xk = tid >> 4;
    const int xj = (tid & 15) * 4;
    const float* yb = y2 + (size_t)n * Cb * HW;
    float acc[4][4] = {};
    for (int k0 = 0; k0 < Cb; k0 += KT) {
        __syncthreads();
        float4 wv = *(const float4*)(w3 + (size_t)(cb + wr) * Cb + k0 + wk);
        Wt[wk + 0][wr] = wv.x; Wt[wk + 1][wr] = wv.y;
        Wt[wk + 2][wr] = wv.z; Wt[wk + 3][wr] = wv.w;
        float4 xv = make_float4(0.f, 0.f, 0.f, 0.f);
        if (pb + xj < HW) xv = *(const float4*)(yb + (size_t)(k0 + xk) * HW + pb + xj);
        *(float4*)&Xt[xk][xj] = xv;
        __syncthreads();
        #pragma unroll
        for (int kk = 0; kk < KT; ++kk) {
            float4 a4 = *(const float4*)&Wt[kk][ty * 4];
            float4 b4 = *(const float4*)&Xt[kk][tx * 4];
            float a[4] = {a4.x, a4.y, a4.z, a4.w};
            float bb[4] = {b4.x, b4.y, b4.z, b4.w};
            #pragma unroll
            for (int i2 = 0; i2 < 4; ++i2)
                #pragma unroll
                for (int j2 = 0; j2 < 4; ++j2)
                    acc[i2][j2] = fmaf(a[i2], bb[j2], acc[i2][j2]);
        }
    }
    #pragma unroll
    for (int i2 = 0; i2 < 4; ++i2) {
        int co = cb + ty * 4 + i2;
        float sc = g[co] * rsqrtf(v[co]);
        float bi = b[co] - m[co] * sc;
        int p4 = pb + tx * 4;
        if (p4 < HW) {
            size_t off = (size_t)(n * Cout + co) * HW + p4;
            float4 r = *(const float4*)(x + off);
            float4 o;
            float t0 = fmaf(acc[i2][0], sc, bi) + r.x; o.x = t0 > 0.f ? t0 : 0.f;
            float t1 = fmaf(acc[i2][1], sc, bi) + r.y; o.y = t1 > 0.f ? t1 : 0.f;
            float t2 = fmaf(acc[i2][2], sc, bi) + r.z; o.z = t2 > 0.f ? t2 : 0.f;
            float t3 = fmaf(acc[i2][3], sc, bi) + r.w; o.w = t3 > 0.f ? t3 : 0.f;
            *(float4*)(out + off) = o;
        }
    }
}

extern "C" void kernel_launch(void* const* d_in, const int* in_sizes, int n_in,
                              void* d_out, int out_size, void* d_ws, size_t ws_size,
                              hipStream_t stream) {
    const float* x  = (const float*)d_in[0];
    const float* w1 = (const float*)d_in[1];
    const float* w2 = (const float*)d_in[2];
    const float* w3 = (const float*)d_in[3];
    const float* g1 = (const float*)d_in[4];
    const float* b1 = (const float*)d_in[5];
    const float* m1 = (const float*)d_in[6];
    const float* v1 = (const float*)d_in[7];
    const float* g2 = (const float*)d_in[8];
    const float* b2 = (const float*)d_in[9];
    const float* m2 = (const float*)d_in[10];
    const float* v2 = (const float*)d_in[11];
    const float* g3 = (const float*)d_in[12];
    const float* b3 = (const float*)d_in[13];
    const float* m3 = (const float*)d_in[14];
    const float* v3 = (const float*)d_in[15];
    float* out = (float*)d_out;

    // workspace layout
    float* y1p = (float*)d_ws;                       // 32*256*900 = 7,372,800 floats
    float* y2  = y1p + (size_t)32 * 256 * 900;       // 32*256*784 = 6,422,528 floats

    const int n4 = (32 * 256 * 900) / 4;             // 1,843,200 float4s
    zero_f4<<<(n4 + 255) / 256, 256, 0, stream>>>((float4*)y1p, n4);

    conv1_bn_relu<<<dim3(13, 4, 32), 256, 0, stream>>>(x, w1, g1, b1, m1, v1, y1p);
    conv2_bn_relu<<<dim3(13, 4, 32), 256, 0, stream>>>(y1p, w2, g2, b2, m2, v2, y2);
    conv3_bn_add_relu<<<dim3(13, 16, 32), 256, 0, stream>>>(y2, w3, g3, b3, m3, v3, x, out);
}

// Round 2
// 355.076 us; speedup vs baseline: 3.7144x; 3.7144x over previous
//
#include <hip/hip_runtime.h>

// SpatialBottleneck — bf16 MFMA implicit-GEMM (NHWC), m97-style structure.
// x[32,1024,28,28] fp32 ->
//   prep:  x -> Xh NHWC bf16 [25088][1024]; w -> bf16 (w2 -> [tap][co][ci]); BN folded
//   conv1: GEMM 25088x256x1024 -> y1p padded NHWC bf16 [32*900][256] (+BN+ReLU)
//   conv2: 9-tap GEMM 25088x256x(9*256)   -> y2 NHWC bf16 [25088][256] (+BN+ReLU)
//   conv3: GEMM 25088x1024x256 + residual -> out NCHW fp32 (+BN+ReLU)
// Tiles: 128(pix) x 128(co), BK=64, 4 waves x 64x64, mfma_f32_16x16x32_bf16.
// Staging: global_load_lds width=16, XOR chunk swizzle (global-side) to kill
// the 128B-row-stride bank conflict while honoring wave-uniform-base DMA.

#define BM 128
#define BNT 128
#define BK 64

typedef __attribute__((ext_vector_type(8))) short short8;
typedef __attribute__((ext_vector_type(4))) float f32x4;

__device__ inline unsigned short f2bf(float f) {
    unsigned int u = __float_as_uint(f);
    u += 0x7fff + ((u >> 16) & 1);            // RNE
    return (unsigned short)(u >> 16);
}

__device__ inline void gload16(const unsigned short* g, unsigned short* l) {
    __builtin_amdgcn_global_load_lds(
        (const __attribute__((address_space(1))) unsigned int*)g,
        (__attribute__((address_space(3))) unsigned int*)l, 16, 0, 0);
}

// ---------------- prep: x NCHW fp32 -> NHWC bf16 ----------------
__global__ __launch_bounds__(256) void prep_x(const float* __restrict__ x,
                                              unsigned short* __restrict__ Xh) {
    __shared__ float t[32][33];
    const int p0 = blockIdx.x * 32, c0 = blockIdx.y * 32, n = blockIdx.z;
    const int tid = threadIdx.x;
    const int pl = tid & 31, cl = tid >> 5;       // load: 8 ci rows/pass
    const float* xb = x + ((size_t)n * 1024 + c0) * 784;
    #pragma unroll
    for (int j = 0; j < 4; ++j) {
        int ci = cl + j * 8;
        int p = p0 + pl;
        t[ci][pl] = (p < 784) ? xb[(size_t)ci * 784 + p] : 0.f;
    }
    __syncthreads();
    const int cl2 = tid & 31, pl2 = tid >> 5;
    #pragma unroll
    for (int j = 0; j < 4; ++j) {
        int p = p0 + pl2 + j * 8;
        if (p < 784)
            Xh[(size_t)(n * 784 + p) * 1024 + c0 + cl2] = f2bf(t[cl2][pl2 + j * 8]);
    }
}

// ---------------- prep: weights -> bf16, w2 -> [tap][co][ci]; BN fold ----------------
__global__ __launch_bounds__(256) void prep_w(
    const float* __restrict__ w1, const float* __restrict__ w2, const float* __restrict__ w3,
    const float* g1, const float* b1, const float* m1, const float* v1,
    const float* g2, const float* b2, const float* m2, const float* v2,
    const float* g3, const float* b3, const float* m3, const float* v3,
    unsigned short* __restrict__ Wb1, unsigned short* __restrict__ Wt2,
    unsigned short* __restrict__ Wb3,
    float* __restrict__ bn1, float* __restrict__ bn2, float* __restrict__ bn3) {
    int i = blockIdx.x * 256 + threadIdx.x;
    if (i < 262144) Wb1[i] = f2bf(w1[i]);
    if (i < 589824) {
        int kw = i % 3, t1 = i / 3;
        int kh = t1 % 3, t2 = t1 / 3;
        int ci = t2 & 255, co = t2 >> 8;
        Wt2[(size_t)((kh * 3 + kw) * 256 + co) * 256 + ci] = f2bf(w2[i]);
    }
    if (i < 262144) Wb3[i] = f2bf(w3[i]);
    if (i < 256) { float s = g1[i] * rsqrtf(v1[i]); bn1[i] = s; bn1[256 + i] = b1[i] - m1[i] * s; }
    if (i < 256) { float s = g2[i] * rsqrtf(v2[i]); bn2[i] = s; bn2[256 + i] = b2[i] - m2[i] * s; }
    if (i < 1024) { float s = g3[i] * rsqrtf(v3[i]); bn3[i] = s; bn3[1024 + i] = b3[i] - m3[i] * s; }
}

__global__ __launch_bounds__(256) void zero16(uint4* __restrict__ p, int n) {
    int i = blockIdx.x * 256 + threadIdx.x;
    if (i < n) p[i] = make_uint4(0u, 0u, 0u, 0u);
}

// ---------------- MFMA implicit-GEMM conv ----------------
// LAYER 1: out = y1p padded NHWC bf16, LAYER 2: y2 NHWC bf16, LAYER 3: fp32 NCHW + resid
template <int CX, int NTAPS, int LAYER>
__global__ __launch_bounds__(256) void conv_mfma(
    const unsigned short* __restrict__ Xg, const unsigned short* __restrict__ Wg,
    const float* __restrict__ bn, int nco,
    const float* __restrict__ residual,
    unsigned short* __restrict__ obf, float* __restrict__ ofp) {
    __shared__ __align__(16) unsigned short Xs[BM * BK];
    __shared__ __align__(16) unsigned short Ws[BNT * BK];
    const int tid = threadIdx.x;
    const int wave = tid >> 6, lane = tid & 63;
    const int quad = lane >> 4, l15 = lane & 15;
    const int Pb = blockIdx.x * BM;
    const int cb = blockIdx.y * BNT;
    const int wco = (wave & 1) * 64;
    const int wpx = (wave >> 1) * 64;

    // staging precompute: 4 rounds, slot = t*256 + tid -> (row, phys chunk)
    int rowt[4], cso[4];
    size_t xrow[4];
    #pragma unroll
    for (int t = 0; t < 4; ++t) {
        int slot = t * 256 + tid;
        int row = slot >> 3;
        int c = slot & 7;
        rowt[t] = row;
        cso[t] = ((c ^ (row & 7)) * 8);           // element offset of global chunk
        if (LAYER == 2) {
            int P = Pb + row;
            int n = P / 784, rem = P - n * 784;
            int h = rem / 28, w = rem - h * 28;
            xrow[t] = (size_t)n * 900 + h * 30 + w;   // padded-row base (tap adds kh*30+kw)
        } else {
            xrow[t] = (size_t)(Pb + row);
        }
    }

    f32x4 acc[4][4];
    #pragma unroll
    for (int i = 0; i < 4; ++i)
        #pragma unroll
        for (int j = 0; j < 4; ++j)
            acc[i][j] = (f32x4){0.f, 0.f, 0.f, 0.f};

    for (int tap = 0; tap < NTAPS; ++tap) {
        const int tapofs = (NTAPS == 9) ? ((tap / 3) * 30 + (tap % 3)) : 0;
        const unsigned short* Wtap = Wg + (size_t)tap * 256 * CX;
        for (int k0 = 0; k0 < CX; k0 += BK) {
            __syncthreads();
            #pragma unroll
            for (int t = 0; t < 4; ++t) {
                unsigned short* xl = Xs + (size_t)(t * 256 + wave * 64) * 8;
                unsigned short* wl = Ws + (size_t)(t * 256 + wave * 64) * 8;
                const unsigned short* gx = Xg + (xrow[t] + tapofs) * (size_t)CX + k0 + cso[t];
                const unsigned short* gw = Wtap + (size_t)(cb + rowt[t]) * CX + k0 + cso[t];
                gload16(gx, xl);
                gload16(gw, wl);
            }
            __syncthreads();
            #pragma unroll
            for (int kk = 0; kk < BK; kk += 32) {
                short8 af[4], bf[4];
                const int cbase = kk >> 3;            // 0 or 4
                #pragma unroll
                for (int wi = 0; wi < 4; ++wi) {
                    int row = wco + wi * 16 + l15;
                    int ch = (cbase + quad) ^ (row & 7);
                    af[wi] = *(const short8*)(Ws + (row * 8 + ch) * 8);
                }
                #pragma unroll
                for (int wj = 0; wj < 4; ++wj) {
                    int row = wpx + wj * 16 + l15;
                    int ch = (cbase + quad) ^ (row & 7);
                    bf[wj] = *(const short8*)(Xs + (row * 8 + ch) * 8);
                }
                #pragma unroll
                for (int wi = 0; wi < 4; ++wi)
                    #pragma unroll
                    for (int wj = 0; wj < 4; ++wj)
                        acc[wi][wj] = __builtin_amdgcn_mfma_f32_16x16x32_bf16(
                            af[wi], bf[wj], acc[wi][wj], 0, 0, 0);
            }
        }
    }

    // epilogue: lane holds C[co = quad*4+r (a-slot)][pix = l15 (b-slot)]
    #pragma unroll
    for (int wi = 0; wi < 4; ++wi) {
        int co0 = cb + wco + wi * 16 + quad * 4;
        f32x4 sc = *(const f32x4*)(bn + co0);
        f32x4 bi = *(const f32x4*)(bn + nco + co0);
        #pragma unroll
        for (int wj = 0; wj < 4; ++wj) {
            int P = Pb + wpx + wj * 16 + l15;
            if (LAYER == 3) {
                int n = P / 784, p = P - n * 784;
                #pragma unroll
                for (int r = 0; r < 4; ++r) {
                    size_t off = ((size_t)n * 1024 + co0 + r) * 784 + p;
                    float v = fmaf(acc[wi][wj][r], sc[r], bi[r]) + residual[off];
                    ofp[off] = v > 0.f ? v : 0.f;
                }
            } else {
                size_t orow;
                if (LAYER == 1) {
                    int n = P / 784, rem = P - n * 784;
                    int h = rem / 28, w = rem - h * 28;
                    orow = (size_t)n * 900 + (h + 1) * 30 + (w + 1);
                } else {
                    orow = (size_t)P;
                }
                float v0 = fmaf(acc[wi][wj][0], sc[0], bi[0]); v0 = v0 > 0.f ? v0 : 0.f;
                float v1 = fmaf(acc[wi][wj][1], sc[1], bi[1]); v1 = v1 > 0.f ? v1 : 0.f;
                float v2 = fmaf(acc[wi][wj][2], sc[2], bi[2]); v2 = v2 > 0.f ? v2 : 0.f;
                float v3 = fmaf(acc[wi][wj][3], sc[3], bi[3]); v3 = v3 > 0.f ? v3 : 0.f;
                uint2 pk;
                pk.x = (unsigned)f2bf(v0) | ((unsigned)f2bf(v1) << 16);
                pk.y = (unsigned)f2bf(v2) | ((unsigned)f2bf(v3) << 16);
                *(uint2*)(obf + orow * 256 + co0) = pk;
            }
        }
    }
}

extern "C" void kernel_launch(void* const* d_in, const int* in_sizes, int n_in,
                              void* d_out, int out_size, void* d_ws, size_t ws_size,
                              hipStream_t stream) {
    const float* x  = (const float*)d_in[0];
    const float* w1 = (const float*)d_in[1];
    const float* w2 = (const float*)d_in[2];
    const float* w3 = (const float*)d_in[3];
    const float* g1 = (const float*)d_in[4];  const float* b1 = (const float*)d_in[5];
    const float* m1 = (const float*)d_in[6];  const float* v1 = (const float*)d_in[7];
    const float* g2 = (const float*)d_in[8];  const float* b2 = (const float*)d_in[9];
    const float* m2 = (const float*)d_in[10]; const float* v2 = (const float*)d_in[11];
    const float* g3 = (const float*)d_in[12]; const float* b3 = (const float*)d_in[13];
    const float* m3 = (const float*)d_in[14]; const float* v3 = (const float*)d_in[15];
    float* out = (float*)d_out;

    char* ws = (char*)d_ws;
    unsigned short* Xh  = (unsigned short*)(ws);                    // 25088*1024*2 = 51,380,224
    unsigned short* y1p = (unsigned short*)(ws + 51380224);         // 32*900*256*2 = 14,745,600
    unsigned short* y2  = (unsigned short*)(ws + 66125824);         // 25088*256*2  = 12,845,056
    unsigned short* Wb1 = (unsigned short*)(ws + 78970880);         // 524,288
    unsigned short* Wt2 = (unsigned short*)(ws + 79495168);         // 1,179,648
    unsigned short* Wb3 = (unsigned short*)(ws + 80674816);         // 524,288
    float* bn1 = (float*)(ws + 81199104);                           // 2 KB
    float* bn2 = (float*)(ws + 81201152);                           // 2 KB
    float* bn3 = (float*)(ws + 81203200);                           // 8 KB

    prep_x<<<dim3(25, 32, 32), 256, 0, stream>>>(x, Xh);
    prep_w<<<2304, 256, 0, stream>>>(w1, w2, w3,
                                     g1, b1, m1, v1, g2, b2, m2, v2, g3, b3, m3, v3,
                                     Wb1, Wt2, Wb3, bn1, bn2, bn3);
    zero16<<<3600, 256, 0, stream>>>((uint4*)y1p, 921600);

    // conv1: K=1024, pix-tiles 196, co-tiles 2
    conv_mfma<1024, 1, 1><<<dim3(196, 2), 256, 0, stream>>>(
        Xh, Wb1, bn1, 256, nullptr, y1p, nullptr);
    // conv2: 9 taps x K=256
    conv_mfma<256, 9, 2><<<dim3(196, 2), 256, 0, stream>>>(
        y1p, Wt2, bn2, 256, nullptr, y2, nullptr);
    // conv3: K=256, co-tiles 8, fp32 NCHW out + residual
    conv_mfma<256, 1, 3><<<dim3(196, 8), 256, 0, stream>>>(
        y2, Wb3, bn3, 1024, x, nullptr, out);
}

// Round 4
// 343.153 us; speedup vs baseline: 3.8434x; 1.0347x over previous
//
#include <hip/hip_runtime.h>

// SpatialBottleneck — bf16 MFMA implicit-GEMM (NHWC), m97-style structure.
// Round 4: fixes round-3 bug — bf16 epilogue LDS-transpose reader dropped the
// block channel base `cb` in the global store (cb=128 blocks clobbered co 0..127).

#define BM 128
#define BNT 128
#define BK 64

typedef __attribute__((ext_vector_type(8))) short short8;
typedef __attribute__((ext_vector_type(4))) float f32x4;

__device__ inline unsigned short f2bf(float f) {
    unsigned int u = __float_as_uint(f);
    u += 0x7fff + ((u >> 16) & 1);            // RNE
    return (unsigned short)(u >> 16);
}

__device__ inline void gload16(const unsigned short* g, unsigned short* l) {
    __builtin_amdgcn_global_load_lds(
        (const __attribute__((address_space(1))) unsigned int*)g,
        (__attribute__((address_space(3))) unsigned int*)l, 16, 0, 0);
}

// ---------------- prep: x NCHW fp32 -> NHWC bf16 ----------------
__global__ __launch_bounds__(256) void prep_x(const float* __restrict__ x,
                                              unsigned short* __restrict__ Xh) {
    __shared__ float t[32][33];
    const int p0 = blockIdx.x * 32, c0 = blockIdx.y * 32, n = blockIdx.z;
    const int tid = threadIdx.x;
    const int pl = tid & 31, cl = tid >> 5;
    const float* xb = x + ((size_t)n * 1024 + c0) * 784;
    #pragma unroll
    for (int j = 0; j < 4; ++j) {
        int ci = cl + j * 8;
        int p = p0 + pl;
        t[ci][pl] = (p < 784) ? xb[(size_t)ci * 784 + p] : 0.f;
    }
    __syncthreads();
    const int c2 = (tid & 15) * 2, pr = tid >> 4;
    #pragma unroll
    for (int j = 0; j < 2; ++j) {
        int p = p0 + pr + j * 16;
        if (p < 784) {
            unsigned int pk = (unsigned)f2bf(t[c2][pr + j * 16]) |
                              ((unsigned)f2bf(t[c2 + 1][pr + j * 16]) << 16);
            *(unsigned int*)(Xh + (size_t)(n * 784 + p) * 1024 + c0 + c2) = pk;
        }
    }
}

// ---------------- prep: weights -> bf16, w2 -> [tap][co][ci]; BN fold ----------------
__global__ __launch_bounds__(256) void prep_w(
    const float* __restrict__ w1, const float* __restrict__ w2, const float* __restrict__ w3,
    const float* g1, const float* b1, const float* m1, const float* v1,
    const float* g2, const float* b2, const float* m2, const float* v2,
    const float* g3, const float* b3, const float* m3, const float* v3,
    unsigned short* __restrict__ Wb1, unsigned short* __restrict__ Wt2,
    unsigned short* __restrict__ Wb3,
    float* __restrict__ bn1, float* __restrict__ bn2, float* __restrict__ bn3) {
    int i = blockIdx.x * 256 + threadIdx.x;
    if (i < 262144) Wb1[i] = f2bf(w1[i]);
    if (i < 589824) {
        int kw = i % 3, t1 = i / 3;
        int kh = t1 % 3, t2 = t1 / 3;
        int ci = t2 & 255, co = t2 >> 8;
        Wt2[(size_t)((kh * 3 + kw) * 256 + co) * 256 + ci] = f2bf(w2[i]);
    }
    if (i < 262144) Wb3[i] = f2bf(w3[i]);
    if (i < 256) { float s = g1[i] * rsqrtf(v1[i]); bn1[i] = s; bn1[256 + i] = b1[i] - m1[i] * s; }
    if (i < 256) { float s = g2[i] * rsqrtf(v2[i]); bn2[i] = s; bn2[256 + i] = b2[i] - m2[i] * s; }
    if (i < 1024) { float s = g3[i] * rsqrtf(v3[i]); bn3[i] = s; bn3[1024 + i] = b3[i] - m3[i] * s; }
}

__global__ __launch_bounds__(256) void zero16(uint4* __restrict__ p, int n) {
    int i = blockIdx.x * 256 + threadIdx.x;
    if (i < n) p[i] = make_uint4(0u, 0u, 0u, 0u);
}

// ---------------- MFMA implicit-GEMM conv body ----------------
// LAYER 1: y1p padded NHWC bf16; LAYER 2: y2 NHWC bf16; LAYER 3: fp32 NCHW + resid
template <int CX, int NTAPS, int LAYER>
__device__ __forceinline__ void conv_body(
    const unsigned short* __restrict__ Xg, const unsigned short* __restrict__ Wg,
    const float* __restrict__ bn, int nco,
    const float* __restrict__ residual,
    unsigned short* __restrict__ obf, float* __restrict__ ofp) {
    __shared__ __align__(16) char smem[LAYER == 3 ? 33792 : 32768];
    unsigned short* Xs = (unsigned short*)smem;
    unsigned short* Ws = (unsigned short*)(smem + 16384);
    const int tid = threadIdx.x;
    const int wave = tid >> 6, lane = tid & 63;
    const int quad = lane >> 4, l15 = lane & 15;
    const int Pb = blockIdx.x * BM;
    const int cb = blockIdx.y * BNT;
    const int wco = (wave & 1) * 64;
    const int wpx = (wave >> 1) * 64;

    // staging precompute: 4 rounds, slot = t*256 + tid -> (row, phys chunk)
    int rowt[4], cso[4];
    size_t xrow[4];
    #pragma unroll
    for (int t = 0; t < 4; ++t) {
        int slot = t * 256 + tid;
        int row = slot >> 3;
        int c = slot & 7;
        rowt[t] = row;
        cso[t] = ((c ^ (row & 7)) * 8);           // element offset of global chunk
        if (LAYER == 2) {
            int P = Pb + row;
            int n = P / 784, rem = P - n * 784;
            int h = rem / 28, w = rem - h * 28;
            xrow[t] = (size_t)n * 900 + h * 30 + w;   // padded-row base (tap adds kh*30+kw)
        } else {
            xrow[t] = (size_t)(Pb + row);
        }
    }

    f32x4 acc[4][4];
    #pragma unroll
    for (int i = 0; i < 4; ++i)
        #pragma unroll
        for (int j = 0; j < 4; ++j)
            acc[i][j] = (f32x4){0.f, 0.f, 0.f, 0.f};

    for (int tap = 0; tap < NTAPS; ++tap) {
        const int tapofs = (NTAPS == 9) ? ((tap / 3) * 30 + (tap % 3)) : 0;
        const unsigned short* Wtap = Wg + (size_t)tap * 256 * CX;
        for (int k0 = 0; k0 < CX; k0 += BK) {
            __syncthreads();
            #pragma unroll
            for (int t = 0; t < 4; ++t) {
                unsigned short* xl = Xs + (size_t)(t * 256 + wave * 64) * 8;
                unsigned short* wl = Ws + (size_t)(t * 256 + wave * 64) * 8;
                const unsigned short* gx = Xg + (xrow[t] + tapofs) * (size_t)CX + k0 + cso[t];
                const unsigned short* gw = Wtap + (size_t)(cb + rowt[t]) * CX + k0 + cso[t];
                gload16(gx, xl);
                gload16(gw, wl);
            }
            __syncthreads();
            #pragma unroll
            for (int kk = 0; kk < BK; kk += 32) {
                short8 af[4], bf[4];
                const int cbase = kk >> 3;            // 0 or 4
                #pragma unroll
                for (int wi = 0; wi < 4; ++wi) {
                    int row = wco + wi * 16 + l15;
                    int ch = (cbase + quad) ^ (row & 7);
                    af[wi] = *(const short8*)(Ws + (row * 8 + ch) * 8);
                }
                #pragma unroll
                for (int wj = 0; wj < 4; ++wj) {
                    int row = wpx + wj * 16 + l15;
                    int ch = (cbase + quad) ^ (row & 7);
                    bf[wj] = *(const short8*)(Xs + (row * 8 + ch) * 8);
                }
                #pragma unroll
                for (int wi = 0; wi < 4; ++wi)
                    #pragma unroll
                    for (int wj = 0; wj < 4; ++wj)
                        acc[wi][wj] = __builtin_amdgcn_mfma_f32_16x16x32_bf16(
                            af[wi], bf[wj], acc[wi][wj], 0, 0, 0);
            }
        }
    }

    __syncthreads();   // protect smem reuse: all frag reads done before epilogue writes

    if (LAYER == 3) {
        // fp32 NCHW + residual + ReLU, two co-half passes through LDS [64][132] f32
        float* ep = (float*)smem;
        #pragma unroll
        for (int pass = 0; pass < 2; ++pass) {
            if ((wave & 1) == pass) {
                #pragma unroll
                for (int wi = 0; wi < 4; ++wi) {
                    int co0 = cb + wco + wi * 16 + quad * 4;
                    f32x4 sc = *(const f32x4*)(bn + co0);
                    f32x4 bi = *(const f32x4*)(bn + nco + co0);
                    int cr0 = wi * 16 + quad * 4;          // 0..63 local co row
                    #pragma unroll
                    for (int wj = 0; wj < 4; ++wj) {
                        int px = wpx + wj * 16 + l15;      // 0..127
                        #pragma unroll
                        for (int r = 0; r < 4; ++r)
                            ep[(cr0 + r) * 132 + px] = fmaf(acc[wi][wj][r], sc[r], bi[r]);
                    }
                }
            }
            __syncthreads();
            {
                int cr = tid >> 2;                         // 0..63
                int cg = tid & 3;
                int co = cb + pass * 64 + cr;
                #pragma unroll
                for (int k = 0; k < 8; ++k) {
                    int px4 = (cg + 4 * k) * 4;            // 0..124
                    f32x4 v = *(const f32x4*)(ep + cr * 132 + px4);
                    int P = Pb + px4;
                    int n = P / 784, p = P - n * 784;      // px4 mult of 4, 784%4==0
                    size_t off = ((size_t)n * 1024 + co) * 784 + p;
                    float4 rs = *(const float4*)(residual + off);
                    float4 o;
                    o.x = v[0] + rs.x; o.x = o.x > 0.f ? o.x : 0.f;
                    o.y = v[1] + rs.y; o.y = o.y > 0.f ? o.y : 0.f;
                    o.z = v[2] + rs.z; o.z = o.z > 0.f ? o.z : 0.f;
                    o.w = v[3] + rs.w; o.w = o.w > 0.f ? o.w : 0.f;
                    *(float4*)(ofp + off) = o;
                }
            }
            __syncthreads();
        }
    } else {
        // bf16 NHWC (+BN+ReLU), two px-half passes through LDS [64][136] ushort
        unsigned short* ep = (unsigned short*)smem;
        #pragma unroll
        for (int pass = 0; pass < 2; ++pass) {
            if ((wave >> 1) == pass) {
                #pragma unroll
                for (int wi = 0; wi < 4; ++wi) {
                    int co0 = cb + wco + wi * 16 + quad * 4;
                    f32x4 sc = *(const f32x4*)(bn + co0);
                    f32x4 bi = *(const f32x4*)(bn + nco + co0);
                    int col = wco + wi * 16 + quad * 4;    // 0..127 local co
                    #pragma unroll
                    for (int wj = 0; wj < 4; ++wj) {
                        int pxl = wj * 16 + l15;           // 0..63 within pass
                        float v0 = fmaf(acc[wi][wj][0], sc[0], bi[0]); v0 = v0 > 0.f ? v0 : 0.f;
                        float v1 = fmaf(acc[wi][wj][1], sc[1], bi[1]); v1 = v1 > 0.f ? v1 : 0.f;
                        float v2 = fmaf(acc[wi][wj][2], sc[2], bi[2]); v2 = v2 > 0.f ? v2 : 0.f;
                        float v3 = fmaf(acc[wi][wj][3], sc[3], bi[3]); v3 = v3 > 0.f ? v3 : 0.f;
                        uint2 pk;
                        pk.x = (unsigned)f2bf(v0) | ((unsigned)f2bf(v1) << 16);
                        pk.y = (unsigned)f2bf(v2) | ((unsigned)f2bf(v3) << 16);
                        *(uint2*)(ep + pxl * 136 + col) = pk;
                    }
                }
            }
            __syncthreads();
            {
                int pxl = tid >> 2;                        // 0..63
                int cg = tid & 3;
                int P = Pb + pass * 64 + pxl;
                size_t orow;
                if (LAYER == 1) {
                    int n = P / 784, rem = P - n * 784;
                    int h = rem / 28, w = rem - h * 28;
                    orow = (size_t)n * 900 + (h + 1) * 30 + (w + 1);
                } else {
                    orow = (size_t)P;
                }
                #pragma unroll
                for (int k = 0; k < 4; ++k) {
                    int cc = (cg + 4 * k) * 8;             // ushort offset 0..120
                    uint4 v = *(const uint4*)(ep + pxl * 136 + cc);
                    *(uint4*)(obf + orow * 256 + cb + cc) = v;   // FIX: + cb
                }
            }
            __syncthreads();
        }
    }
}

__global__ __launch_bounds__(256) void conv1_mfma(
    const unsigned short* __restrict__ Xg, const unsigned short* __restrict__ Wg,
    const float* __restrict__ bn, unsigned short* __restrict__ obf) {
    conv_body<1024, 1, 1>(Xg, Wg, bn, 256, nullptr, obf, nullptr);
}
__global__ __launch_bounds__(256) void conv2_mfma(
    const unsigned short* __restrict__ Xg, const unsigned short* __restrict__ Wg,
    const float* __restrict__ bn, unsigned short* __restrict__ obf) {
    conv_body<256, 9, 2>(Xg, Wg, bn, 256, nullptr, obf, nullptr);
}
__global__ __launch_bounds__(256) void conv3_mfma(
    const unsigned short* __restrict__ Xg, const unsigned short* __restrict__ Wg,
    const float* __restrict__ bn, const float* __restrict__ residual,
    float* __restrict__ ofp) {
    conv_body<256, 1, 3>(Xg, Wg, bn, 1024, residual, nullptr, ofp);
}

extern "C" void kernel_launch(void* const* d_in, const int* in_sizes, int n_in,
                              void* d_out, int out_size, void* d_ws, size_t ws_size,
                              hipStream_t stream) {
    const float* x  = (const float*)d_in[0];
    const float* w1 = (const float*)d_in[1];
    const float* w2 = (const float*)d_in[2];
    const float* w3 = (const float*)d_in[3];
    const float* g1 = (const float*)d_in[4];  const float* b1 = (const float*)d_in[5];
    const float* m1 = (const float*)d_in[6];  const float* v1 = (const float*)d_in[7];
    const float* g2 = (const float*)d_in[8];  const float* b2 = (const float*)d_in[9];
    const float* m2 = (const float*)d_in[10]; const float* v2 = (const float*)d_in[11];
    const float* g3 = (const float*)d_in[12]; const float* b3 = (const float*)d_in[13];
    const float* m3 = (const float*)d_in[14]; const float* v3 = (const float*)d_in[15];
    float* out = (float*)d_out;

    char* ws = (char*)d_ws;
    unsigned short* Xh  = (unsigned short*)(ws);                    // 25088*1024*2 = 51,380,224
    unsigned short* y1p = (unsigned short*)(ws + 51380224);         // 32*900*256*2 = 14,745,600
    unsigned short* y2  = (unsigned short*)(ws + 66125824);         // 25088*256*2  = 12,845,056
    unsigned short* Wb1 = (unsigned short*)(ws + 78970880);         // 524,288
    unsigned short* Wt2 = (unsigned short*)(ws + 79495168);         // 1,179,648
    unsigned short* Wb3 = (unsigned short*)(ws + 80674816);         // 524,288
    float* bn1 = (float*)(ws + 81199104);                           // 2 KB
    float* bn2 = (float*)(ws + 81201152);                           // 2 KB
    float* bn3 = (float*)(ws + 81203200);                           // 8 KB

    prep_x<<<dim3(25, 32, 32), 256, 0, stream>>>(x, Xh);
    prep_w<<<2304, 256, 0, stream>>>(w1, w2, w3,
                                     g1, b1, m1, v1, g2, b2, m2, v2, g3, b3, m3, v3,
                                     Wb1, Wt2, Wb3, bn1, bn2, bn3);
    zero16<<<3600, 256, 0, stream>>>((uint4*)y1p, 921600);

    conv1_mfma<<<dim3(196, 2), 256, 0, stream>>>(Xh, Wb1, bn1, y1p);
    conv2_mfma<<<dim3(196, 2), 256, 0, stream>>>(y1p, Wt2, bn2, y2);
    conv3_mfma<<<dim3(196, 8), 256, 0, stream>>>(y2, Wb3, bn3, x, out);
}

// Round 5
// 325.031 us; speedup vs baseline: 4.0577x; 1.0558x over previous
//
#include <hip/hip_runtime.h>

// SpatialBottleneck — bf16 MFMA implicit-GEMM (NHWC), m97-style structure.
// Round 5: prep_x eliminated — conv1 stages x NCHW fp32 directly (register
// transpose + f2bf pack + conflict-free swizzled ds_write). Border-only zero
// for y1p padding (1.9 MB instead of 14.7 MB).

#define BM 128
#define BNT 128
#define BK 64

typedef __attribute__((ext_vector_type(8))) short short8;
typedef __attribute__((ext_vector_type(4))) float f32x4;

__device__ inline unsigned short f2bf(float f) {
    unsigned int u = __float_as_uint(f);
    u += 0x7fff + ((u >> 16) & 1);            // RNE
    return (unsigned short)(u >> 16);
}

__device__ inline void gload16(const unsigned short* g, unsigned short* l) {
    __builtin_amdgcn_global_load_lds(
        (const __attribute__((address_space(1))) unsigned int*)g,
        (__attribute__((address_space(3))) unsigned int*)l, 16, 0, 0);
}

// ---------------- prep: weights -> bf16, w2 -> [tap][co][ci]; BN fold ----------------
__global__ __launch_bounds__(256) void prep_w(
    const float* __restrict__ w1, const float* __restrict__ w2, const float* __restrict__ w3,
    const float* g1, const float* b1, const float* m1, const float* v1,
    const float* g2, const float* b2, const float* m2, const float* v2,
    const float* g3, const float* b3, const float* m3, const float* v3,
    unsigned short* __restrict__ Wb1, unsigned short* __restrict__ Wt2,
    unsigned short* __restrict__ Wb3,
    float* __restrict__ bn1, float* __restrict__ bn2, float* __restrict__ bn3) {
    int i = blockIdx.x * 256 + threadIdx.x;
    if (i < 262144) Wb1[i] = f2bf(w1[i]);
    if (i < 589824) {
        int kw = i % 3, t1 = i / 3;
        int kh = t1 % 3, t2 = t1 / 3;
        int ci = t2 & 255, co = t2 >> 8;
        Wt2[(size_t)((kh * 3 + kw) * 256 + co) * 256 + ci] = f2bf(w2[i]);
    }
    if (i < 262144) Wb3[i] = f2bf(w3[i]);
    if (i < 256) { float s = g1[i] * rsqrtf(v1[i]); bn1[i] = s; bn1[256 + i] = b1[i] - m1[i] * s; }
    if (i < 256) { float s = g2[i] * rsqrtf(v2[i]); bn2[i] = s; bn2[256 + i] = b2[i] - m2[i] * s; }
    if (i < 1024) { float s = g3[i] * rsqrtf(v3[i]); bn3[i] = s; bn3[1024 + i] = b3[i] - m3[i] * s; }
}

// Zero only the 116 border cells per image of y1p [32][900][256] (conv1 fills interior).
__global__ __launch_bounds__(256) void border_zero(uint4* __restrict__ y1p) {
    int i = blockIdx.x * 256 + threadIdx.x;      // 464*256 = 118784 = 32*116*32
    int ch8 = i & 31;
    int t = i >> 5;
    int cell = t % 116;
    int n = t / 116;
    int h, w;
    if (cell < 30)      { h = 0;          w = cell; }
    else if (cell < 60) { h = 29;         w = cell - 30; }
    else if (cell < 88) { h = cell - 59;  w = 0; }
    else                { h = cell - 87;  w = 29; }
    y1p[((size_t)n * 900 + h * 30 + w) * 32 + ch8] = make_uint4(0u, 0u, 0u, 0u);
}

// ---------------- MFMA implicit-GEMM conv body ----------------
// LAYER 1: x fp32 NCHW in (fused transpose/convert), y1p padded NHWC bf16 out
// LAYER 2: y1p in (9-tap), y2 NHWC bf16 out
// LAYER 3: y2 in, fp32 NCHW out + residual
template <int CX, int NTAPS, int LAYER>
__device__ __forceinline__ void conv_body(
    const float* __restrict__ Xf,
    const unsigned short* __restrict__ Xg, const unsigned short* __restrict__ Wg,
    const float* __restrict__ bn, int nco,
    const float* __restrict__ residual,
    unsigned short* __restrict__ obf, float* __restrict__ ofp) {
    __shared__ __align__(16) char smem[LAYER == 3 ? 33792 : 32768];
    unsigned short* Xs = (unsigned short*)smem;
    unsigned short* Ws = (unsigned short*)(smem + 16384);
    const int tid = threadIdx.x;
    const int wave = tid >> 6, lane = tid & 63;
    const int quad = lane >> 4, l15 = lane & 15;
    const int Pb = blockIdx.x * BM;
    const int cb = blockIdx.y * BNT;
    const int wco = (wave & 1) * 64;
    const int wpx = (wave >> 1) * 64;

    // gload16 staging precompute (W always; X for layers 2/3)
    int rowt[4], cso[4];
    size_t xrow[4];
    #pragma unroll
    for (int t = 0; t < 4; ++t) {
        int slot = t * 256 + tid;
        int row = slot >> 3;
        int c = slot & 7;
        rowt[t] = row;
        cso[t] = ((c ^ (row & 7)) * 8);           // element offset of global chunk
        if (LAYER == 2) {
            int P = Pb + row;
            int n = P / 784, rem = P - n * 784;
            int h = rem / 28, w = rem - h * 28;
            xrow[t] = (size_t)n * 900 + h * 30 + w;   // padded-row base (tap adds kh*30+kw)
        } else {
            xrow[t] = (size_t)(Pb + row);
        }
    }

    // LAYER 1: fused-transpose staging precompute (per 4 rounds)
    const int cp = tid & 31;                      // channel-pair 0..31
    size_t xbase[4];
    int plr[4];
    if (LAYER == 1) {
        #pragma unroll
        for (int r = 0; r < 4; ++r) {
            int pl = ((tid >> 5) + r * 8) * 4;    // 0..124
            int P = Pb + pl;
            int n = P / 784, p = P - n * 784;     // float4 never crosses n (784%4==0)
            plr[r] = pl;
            xbase[r] = ((size_t)n * 1024 + 2 * cp) * 784 + p;
        }
    }

    f32x4 acc[4][4];
    #pragma unroll
    for (int i = 0; i < 4; ++i)
        #pragma unroll
        for (int j = 0; j < 4; ++j)
            acc[i][j] = (f32x4){0.f, 0.f, 0.f, 0.f};

    for (int tap = 0; tap < NTAPS; ++tap) {
        const int tapofs = (NTAPS == 9) ? ((tap / 3) * 30 + (tap % 3)) : 0;
        const unsigned short* Wtap = Wg + (size_t)tap * 256 * CX;
        for (int k0 = 0; k0 < CX; k0 += BK) {
            __syncthreads();
            #pragma unroll
            for (int t = 0; t < 4; ++t) {
                unsigned short* wl = Ws + (size_t)(t * 256 + wave * 64) * 8;
                gload16(Wtap + (size_t)(cb + rowt[t]) * CX + k0 + cso[t], wl);
            }
            if (LAYER == 1) {
                #pragma unroll
                for (int r = 0; r < 4; ++r) {
                    const float* src = Xf + xbase[r] + (size_t)k0 * 784;
                    float4 a = *(const float4*)src;
                    float4 b = *(const float4*)(src + 784);
                    float av[4] = {a.x, a.y, a.z, a.w};
                    float bv[4] = {b.x, b.y, b.z, b.w};
                    #pragma unroll
                    for (int j = 0; j < 4; ++j) {
                        unsigned u = (unsigned)f2bf(av[j]) | ((unsigned)f2bf(bv[j]) << 16);
                        int row = plr[r] + j;
                        int dw = row * 32 + (((cp >> 2) ^ (row & 7)) << 2) + (cp & 3);
                        ((unsigned*)Xs)[dw] = u;
                    }
                }
            } else {
                #pragma unroll
                for (int t = 0; t < 4; ++t) {
                    unsigned short* xl = Xs + (size_t)(t * 256 + wave * 64) * 8;
                    gload16(Xg + (xrow[t] + tapofs) * (size_t)CX + k0 + cso[t], xl);
                }
            }
            __syncthreads();
            #pragma unroll
            for (int kk = 0; kk < BK; kk += 32) {
                short8 af[4], bf[4];
                const int cbase = kk >> 3;            // 0 or 4
                #pragma unroll
                for (int wi = 0; wi < 4; ++wi) {
                    int row = wco + wi * 16 + l15;
                    int ch = (cbase + quad) ^ (row & 7);
                    af[wi] = *(const short8*)(Ws + (row * 8 + ch) * 8);
                }
                #pragma unroll
                for (int wj = 0; wj < 4; ++wj) {
                    int row = wpx + wj * 16 + l15;
                    int ch = (cbase + quad) ^ (row & 7);
                    bf[wj] = *(const short8*)(Xs + (row * 8 + ch) * 8);
                }
                #pragma unroll
                for (int wi = 0; wi < 4; ++wi)
                    #pragma unroll
                    for (int wj = 0; wj < 4; ++wj)
                        acc[wi][wj] = __builtin_amdgcn_mfma_f32_16x16x32_bf16(
                            af[wi], bf[wj], acc[wi][wj], 0, 0, 0);
            }
        }
    }

    __syncthreads();   // protect smem reuse: all frag reads done before epilogue writes

    if (LAYER == 3) {
        // fp32 NCHW + residual + ReLU, two co-half passes through LDS [64][132] f32
        float* ep = (float*)smem;
        #pragma unroll
        for (int pass = 0; pass < 2; ++pass) {
            if ((wave & 1) == pass) {
                #pragma unroll
                for (int wi = 0; wi < 4; ++wi) {
                    int co0 = cb + wco + wi * 16 + quad * 4;
                    f32x4 sc = *(const f32x4*)(bn + co0);
                    f32x4 bi = *(const f32x4*)(bn + nco + co0);
                    int cr0 = wi * 16 + quad * 4;          // 0..63 local co row
                    #pragma unroll
                    for (int wj = 0; wj < 4; ++wj) {
                        int px = wpx + wj * 16 + l15;      // 0..127
                        #pragma unroll
                        for (int r = 0; r < 4; ++r)
                            ep[(cr0 + r) * 132 + px] = fmaf(acc[wi][wj][r], sc[r], bi[r]);
                    }
                }
            }
            __syncthreads();
            {
                int cr = tid >> 2;                         // 0..63
                int cg = tid & 3;
                int co = cb + pass * 64 + cr;
                #pragma unroll
                for (int k = 0; k < 8; ++k) {
                    int px4 = (cg + 4 * k) * 4;            // 0..124
                    f32x4 v = *(const f32x4*)(ep + cr * 132 + px4);
                    int P = Pb + px4;
                    int n = P / 784, p = P - n * 784;
                    size_t off = ((size_t)n * 1024 + co) * 784 + p;
                    float4 rs = *(const float4*)(residual + off);
                    float4 o;
                    o.x = v[0] + rs.x; o.x = o.x > 0.f ? o.x : 0.f;
                    o.y = v[1] + rs.y; o.y = o.y > 0.f ? o.y : 0.f;
                    o.z = v[2] + rs.z; o.z = o.z > 0.f ? o.z : 0.f;
                    o.w = v[3] + rs.w; o.w = o.w > 0.f ? o.w : 0.f;
                    *(float4*)(ofp + off) = o;
                }
            }
            __syncthreads();
        }
    } else {
        // bf16 NHWC (+BN+ReLU), two px-half passes through LDS [64][136] ushort
        unsigned short* ep = (unsigned short*)smem;
        #pragma unroll
        for (int pass = 0; pass < 2; ++pass) {
            if ((wave >> 1) == pass) {
                #pragma unroll
                for (int wi = 0; wi < 4; ++wi) {
                    int co0 = cb + wco + wi * 16 + quad * 4;
                    f32x4 sc = *(const f32x4*)(bn + co0);
                    f32x4 bi = *(const f32x4*)(bn + nco + co0);
                    int col = wco + wi * 16 + quad * 4;    // 0..127 local co
                    #pragma unroll
                    for (int wj = 0; wj < 4; ++wj) {
                        int pxl = wj * 16 + l15;           // 0..63 within pass
                        float v0 = fmaf(acc[wi][wj][0], sc[0], bi[0]); v0 = v0 > 0.f ? v0 : 0.f;
                        float v1 = fmaf(acc[wi][wj][1], sc[1], bi[1]); v1 = v1 > 0.f ? v1 : 0.f;
                        float v2 = fmaf(acc[wi][wj][2], sc[2], bi[2]); v2 = v2 > 0.f ? v2 : 0.f;
                        float v3 = fmaf(acc[wi][wj][3], sc[3], bi[3]); v3 = v3 > 0.f ? v3 : 0.f;
                        uint2 pk;
                        pk.x = (unsigned)f2bf(v0) | ((unsigned)f2bf(v1) << 16);
                        pk.y = (unsigned)f2bf(v2) | ((unsigned)f2bf(v3) << 16);
                        *(uint2*)(ep + pxl * 136 + col) = pk;
                    }
                }
            }
            __syncthreads();
            {
                int pxl = tid >> 2;                        // 0..63
                int cg = tid & 3;
                int P = Pb + pass * 64 + pxl;
                size_t orow;
                if (LAYER == 1) {
                    int n = P / 784, rem = P - n * 784;
                    int h = rem / 28, w = rem - h * 28;
                    orow = (size_t)n * 900 + (h + 1) * 30 + (w + 1);
                } else {
                    orow = (size_t)P;
                }
                #pragma unroll
                for (int k = 0; k < 4; ++k) {
                    int cc = (cg + 4 * k) * 8;             // ushort offset 0..120
                    uint4 v = *(const uint4*)(ep + pxl * 136 + cc);
                    *(uint4*)(obf + orow * 256 + cb + cc) = v;
                }
            }
            __syncthreads();
        }
    }
}

__global__ __launch_bounds__(256) void conv1_mfma(
    const float* __restrict__ Xf, const unsigned short* __restrict__ Wg,
    const float* __restrict__ bn, unsigned short* __restrict__ obf) {
    conv_body<1024, 1, 1>(Xf, nullptr, Wg, bn, 256, nullptr, obf, nullptr);
}
__global__ __launch_bounds__(256) void conv2_mfma(
    const unsigned short* __restrict__ Xg, const unsigned short* __restrict__ Wg,
    const float* __restrict__ bn, unsigned short* __restrict__ obf) {
    conv_body<256, 9, 2>(nullptr, Xg, Wg, bn, 256, nullptr, obf, nullptr);
}
__global__ __launch_bounds__(256) void conv3_mfma(
    const unsigned short* __restrict__ Xg, const unsigned short* __restrict__ Wg,
    const float* __restrict__ bn, const float* __restrict__ residual,
    float* __restrict__ ofp) {
    conv_body<256, 1, 3>(nullptr, Xg, Wg, bn, 1024, residual, nullptr, ofp);
}

extern "C" void kernel_launch(void* const* d_in, const int* in_sizes, int n_in,
                              void* d_out, int out_size, void* d_ws, size_t ws_size,
                              hipStream_t stream) {
    const float* x  = (const float*)d_in[0];
    const float* w1 = (const float*)d_in[1];
    const float* w2 = (const float*)d_in[2];
    const float* w3 = (const float*)d_in[3];
    const float* g1 = (const float*)d_in[4];  const float* b1 = (const float*)d_in[5];
    const float* m1 = (const float*)d_in[6];  const float* v1 = (const float*)d_in[7];
    const float* g2 = (const float*)d_in[8];  const float* b2 = (const float*)d_in[9];
    const float* m2 = (const float*)d_in[10]; const float* v2 = (const float*)d_in[11];
    const float* g3 = (const float*)d_in[12]; const float* b3 = (const float*)d_in[13];
    const float* m3 = (const float*)d_in[14]; const float* v3 = (const float*)d_in[15];
    float* out = (float*)d_out;

    char* ws = (char*)d_ws;
    unsigned short* y1p = (unsigned short*)(ws);                    // 32*900*256*2 = 14,745,600
    unsigned short* y2  = (unsigned short*)(ws + 14745600);         // 25088*256*2  = 12,845,056
    unsigned short* Wb1 = (unsigned short*)(ws + 27590656);         // 524,288
    unsigned short* Wt2 = (unsigned short*)(ws + 28114944);         // 1,179,648
    unsigned short* Wb3 = (unsigned short*)(ws + 29294592);         // 524,288
    float* bn1 = (float*)(ws + 29818880);                           // 2 KB
    float* bn2 = (float*)(ws + 29820928);                           // 2 KB
    float* bn3 = (float*)(ws + 29822976);                           // 8 KB

    prep_w<<<2304, 256, 0, stream>>>(w1, w2, w3,
                                     g1, b1, m1, v1, g2, b2, m2, v2, g3, b3, m3, v3,
                                     Wb1, Wt2, Wb3, bn1, bn2, bn3);
    border_zero<<<464, 256, 0, stream>>>((uint4*)y1p);

    conv1_mfma<<<dim3(196, 2), 256, 0, stream>>>(x, Wb1, bn1, y1p);
    conv2_mfma<<<dim3(196, 2), 256, 0, stream>>>(y1p, Wt2, bn2, y2);
    conv3_mfma<<<dim3(196, 8), 256, 0, stream>>>(y2, Wb3, bn3, x, out);
}